// Round 2
// baseline (558.340 us; speedup 1.0000x reference)
//
#include <hip/hip_runtime.h>

#define NN 8192
#define FF 256
#define OST 260   // osum LDS row stride in floats (breaks bank conflicts, keeps f4 align)

typedef _Float16 h8 __attribute__((ext_vector_type(8)));
typedef _Float16 h4 __attribute__((ext_vector_type(4)));
typedef float    f4 __attribute__((ext_vector_type(4)));
typedef int      i4v __attribute__((ext_vector_type(4)));

// ---------------- Kernel 1: Wh = h@W (fp32 vector), emit s1/s2 + wfrag -------
// grid 256 x 512 thr. Block computes Wh rows [b*32, b*32+32) == k-tile b of the
// PV matmul, and writes them directly in MFMA-B-fragment order:
//   wfrag[(kt*16 + n)*512 + lane*8 + j] = Wh[kt*32 + (lane>>4)*8 + j][n*16 + (lane&15)]
// so k_gat's B-loads are fully coalesced 16 B/lane.
__global__ __launch_bounds__(512) void k_wh(
    const float* __restrict__ h, const float* __restrict__ W,
    const float* __restrict__ a, _Float16* __restrict__ wfrag,
    float* __restrict__ s1, float* __restrict__ s2) {
  __shared__ float hs[32 * 256];        // 32 KB
  __shared__ _Float16 whs[32 * 264];    // 16.5 KB
  const int t = threadIdx.x;
  const int r0 = blockIdx.x * 32;
#pragma unroll
  for (int i = 0; i < 4; ++i) {
    int idx = i * 2048 + t * 4;
    *(f4*)&hs[idx] = *(const f4*)&h[(size_t)r0 * 256 + idx];
  }
  __syncthreads();
  const int lane = t & 63;
  const int wv = t >> 6;        // 0..7
  const int rg = wv * 4;        // 4 rows per wave
  const int c4 = lane * 4;      // 4 cols per lane
  float acc[4][4];
#pragma unroll
  for (int i = 0; i < 4; ++i)
#pragma unroll
    for (int k = 0; k < 4; ++k) acc[i][k] = 0.f;
  for (int f = 0; f < 256; f += 4) {
    f4 w0 = *(const f4*)&W[(f + 0) * 256 + c4];
    f4 w1 = *(const f4*)&W[(f + 1) * 256 + c4];
    f4 w2 = *(const f4*)&W[(f + 2) * 256 + c4];
    f4 w3 = *(const f4*)&W[(f + 3) * 256 + c4];
#pragma unroll
    for (int i = 0; i < 4; ++i) {
      f4 hv = *(const f4*)&hs[(rg + i) * 256 + f];   // wave-uniform LDS broadcast
#pragma unroll
      for (int k = 0; k < 4; ++k)
        acc[i][k] += hv[0] * w0[k] + hv[1] * w1[k] + hv[2] * w2[k] + hv[3] * w3[k];
    }
  }
  float a1v[4], a2v[4];
#pragma unroll
  for (int k = 0; k < 4; ++k) { a1v[k] = a[c4 + k]; a2v[k] = a[256 + c4 + k]; }
#pragma unroll
  for (int i = 0; i < 4; ++i) {
    h4 hh;
    float p1 = 0.f, p2 = 0.f;
#pragma unroll
    for (int k = 0; k < 4; ++k) {
      hh[k] = (_Float16)acc[i][k];
      p1 += acc[i][k] * a1v[k];
      p2 += acc[i][k] * a2v[k];
    }
    *(h4*)&whs[(rg + i) * 264 + c4] = hh;
#pragma unroll
    for (int off = 32; off; off >>= 1) {
      p1 += __shfl_xor(p1, off);
      p2 += __shfl_xor(p2, off);
    }
    if (lane == 0) { s1[r0 + rg + i] = p1; s2[r0 + rg + i] = p2; }
  }
  __syncthreads();
  // emit B-fragments for k-tile kt = blockIdx.x
  {
    const int q = lane >> 4;
    const int m16 = lane & 15;
#pragma unroll
    for (int c = 0; c < 2; ++c) {
      const int n = wv * 2 + c;
      h8 v;
#pragma unroll
      for (int j = 0; j < 8; ++j) v[j] = whs[(q * 8 + j) * 264 + n * 16 + m16];
      *(h8*)&wfrag[(((size_t)blockIdx.x * 16 + n) << 9) + (lane << 3)] = v;
    }
  }
}

// ---------------- Kernel 2: s2max (tiny) -------------------------------------
__global__ __launch_bounds__(1024) void k_s2max(
    const float* __restrict__ s2, float* __restrict__ s2maxp) {
  const int t = threadIdx.x;
  float mx = -1e30f;
  for (int i = t; i < NN; i += 1024) mx = fmaxf(mx, s2[i]);
#pragma unroll
  for (int off = 32; off; off >>= 1) mx = fmaxf(mx, __shfl_xor(mx, off));
  __shared__ float wm[16];
  if ((t & 63) == 0) wm[t >> 6] = mx;
  __syncthreads();
  if (t == 0) {
    float m = wm[0];
#pragma unroll
    for (int i = 1; i < 16; ++i) m = fmaxf(m, wm[i]);
    *s2maxp = m;
  }
}

// ---------------- Kernel 3: fused masked-softmax attention -------------------
// grid 256 x 512 thr. Block = 32 rows x all 256 cols. Wave w handles k-tiles
// w, w+8, ... (k=32 each) for ALL rows/cols -> no cross-wave sharing, ZERO
// barriers in the main loop. Partial O reduced once at the end via LDS atomics.
// Static per-row shift m_r = leaky(s1_r + max(s2)) keeps P in (0,1] (f16-safe).
__global__ __launch_bounds__(512, 2) void k_gat(
    const int* __restrict__ adj, const _Float16* __restrict__ wfrag,
    const float* __restrict__ s1g, const float* __restrict__ s2g,
    const float* __restrict__ s2maxp, float* __restrict__ out) {
  __shared__ float osum[32 * OST];   // 33.3 KB
  __shared__ float lsh[32];
  const int t = threadIdx.x;
  const int lane = t & 63;
  const int wv = t >> 6;          // 0..7
  const int q = lane >> 4;        // 0..3
  const int m16 = lane & 15;
  const int r0 = blockIdx.x * 32;

  for (int i = t; i < 32 * OST; i += 512) osum[i] = 0.f;
  if (t < 32) lsh[t] = 0.f;
  __syncthreads();

  const float s2m = *s2maxp;
  const float s1a = s1g[r0 + m16];
  const float s1b = s1g[r0 + 16 + m16];
  const float miA = fmaxf(s1a + s2m, 0.2f * (s1a + s2m));
  const float miB = fmaxf(s1b + s2m, 0.2f * (s1b + s2m));

  f4 acc0[16], acc1[16];
#pragma unroll
  for (int n = 0; n < 16; ++n)
#pragma unroll
    for (int e = 0; e < 4; ++e) { acc0[n][e] = 0.f; acc1[n][e] = 0.f; }
  float lsumA = 0.f, lsumB = 0.f;

  const size_t rowA = (size_t)(r0 + m16) * NN;
  const size_t rowB = (size_t)(r0 + 16 + m16) * NN;

  i4v cA0, cA1, cB0, cB1;
  f4 cLo, cHi;
  {
    const int k0 = wv * 32 + q * 8;
    cA0 = __builtin_nontemporal_load((const i4v*)&adj[rowA + k0]);
    cA1 = __builtin_nontemporal_load((const i4v*)&adj[rowA + k0 + 4]);
    cB0 = __builtin_nontemporal_load((const i4v*)&adj[rowB + k0]);
    cB1 = __builtin_nontemporal_load((const i4v*)&adj[rowB + k0 + 4]);
    cLo = *(const f4*)&s2g[k0];
    cHi = *(const f4*)&s2g[k0 + 4];
  }

  int kt = wv;
  for (int it = 0; it < 32; ++it) {
    // compute P for this k-tile (A-fragment layout: row m16 / 16+m16, k=q*8+j)
    float pA[8], pB[8];
#pragma unroll
    for (int j = 0; j < 8; ++j) {
      const float s2c = (j < 4) ? cLo[j] : cHi[j - 4];
      const int aA = (j < 4) ? cA0[j] : cA1[j - 4];
      const int aB = (j < 4) ? cB0[j] : cB1[j - 4];
      float uA = s1a + s2c;
      float uB = s1b + s2c;
      float eA = fmaxf(uA, 0.2f * uA);
      float eB = fmaxf(uB, 0.2f * uB);
      float vA = (aA > 0) ? __expf(eA - miA) : 0.f;
      float vB = (aB > 0) ? __expf(eB - miB) : 0.f;
      pA[j] = vA; pB[j] = vB;
      lsumA += vA; lsumB += vB;
    }
    // prefetch next k-tile (distance 1)
    const int ktn = kt + 8;
    i4v nA0, nA1, nB0, nB1; f4 nLo, nHi;
    if (it < 31) {
      const int k0n = ktn * 32 + q * 8;
      nA0 = __builtin_nontemporal_load((const i4v*)&adj[rowA + k0n]);
      nA1 = __builtin_nontemporal_load((const i4v*)&adj[rowA + k0n + 4]);
      nB0 = __builtin_nontemporal_load((const i4v*)&adj[rowB + k0n]);
      nB1 = __builtin_nontemporal_load((const i4v*)&adj[rowB + k0n + 4]);
      nLo = *(const f4*)&s2g[k0n];
      nHi = *(const f4*)&s2g[k0n + 4];
    }
    h8 afA, afB;
#pragma unroll
    for (int j = 0; j < 8; ++j) { afA[j] = (_Float16)pA[j]; afB[j] = (_Float16)pB[j]; }
    // MFMA: 16 n-tiles, B-loads fully coalesced from wfrag
    const _Float16* wf = &wfrag[(size_t)kt << 13];
#pragma unroll
    for (int n = 0; n < 16; ++n) {
      h8 b = *(const h8*)&wf[(n << 9) + (lane << 3)];
      acc0[n] = __builtin_amdgcn_mfma_f32_16x16x32_f16(afA, b, acc0[n], 0, 0, 0);
      acc1[n] = __builtin_amdgcn_mfma_f32_16x16x32_f16(afB, b, acc1[n], 0, 0, 0);
    }
    cA0 = nA0; cA1 = nA1; cB0 = nB0; cB1 = nB1; cLo = nLo; cHi = nHi;
    kt = ktn;
  }

  // row-sum reduce: across q-groups (lanes m16, m16+16, +32, +48), then waves
  lsumA += __shfl_xor(lsumA, 16); lsumA += __shfl_xor(lsumA, 32);
  lsumB += __shfl_xor(lsumB, 16); lsumB += __shfl_xor(lsumB, 32);
  if (q == 0) {
    atomicAdd(&lsh[m16], lsumA);
    atomicAdd(&lsh[16 + m16], lsumB);
  }
  // partial-O reduce across waves (C layout: col=lane&15, row=q*4+reg)
#pragma unroll
  for (int n = 0; n < 16; ++n)
#pragma unroll
    for (int v = 0; v < 4; ++v) {
      atomicAdd(&osum[(q * 4 + v) * OST + n * 16 + m16], acc0[n][v]);
      atomicAdd(&osum[(16 + q * 4 + v) * OST + n * 16 + m16], acc1[n][v]);
    }
  __syncthreads();

  // epilogue: out = elu(O / l), coalesced f4 stores
  const int row = t >> 4;
  const int c0 = (t & 15) * 16;
  const float linv = 1.0f / lsh[row];
#pragma unroll
  for (int i = 0; i < 4; ++i) {
    f4 v = *(const f4*)&osum[row * OST + c0 + i * 4];
    f4 o;
#pragma unroll
    for (int e = 0; e < 4; ++e) {
      float x = v[e] * linv;
      o[e] = (x > 0.f) ? x : (__expf(x) - 1.f);
    }
    *(f4*)&out[(size_t)(r0 + row) * FF + c0 + i * 4] = o;
  }
}

extern "C" void kernel_launch(void* const* d_in, const int* in_sizes, int n_in,
                              void* d_out, int out_size, void* d_ws, size_t ws_size,
                              hipStream_t stream) {
  const float* h   = (const float*)d_in[0];
  const int*   adj = (const int*)d_in[1];
  const float* W   = (const float*)d_in[2];
  const float* a   = (const float*)d_in[3];
  float* out = (float*)d_out;

  char* ws = (char*)d_ws;
  _Float16* wfrag = (_Float16*)ws;                         // 4 MB: Wh in B-frag order
  float* s1    = (float*)(ws + 4u * 1024 * 1024);          // 32 KB
  float* s2    = (float*)(ws + 4u * 1024 * 1024 + 32768);  // 32 KB
  float* s2max = (float*)(ws + 4u * 1024 * 1024 + 65536);  // 4 B

  k_wh<<<256, 512, 0, stream>>>(h, W, a, wfrag, s1, s2);
  k_s2max<<<1, 1024, 0, stream>>>(s2, s2max);
  k_gat<<<256, 512, 0, stream>>>(adj, wfrag, s1, s2, s2max, out);
}